// Round 23
// baseline (251.201 us; speedup 1.0000x reference)
//
#include <hip/hip_runtime.h>
#include <hip/hip_bf16.h>
#include <cstdint>
#include <cstddef>

#define NUM_NODES 500000
#define DIM 128
#define BATCH 131072
#define NBLK (NUM_NODES / 32)     // 15625 exactly

typedef __attribute__((ext_vector_type(8))) short short8;
typedef __attribute__((ext_vector_type(4))) short short4_t;
typedef __attribute__((ext_vector_type(4))) float f32x4;

static __device__ __forceinline__ short f2bf(float f) {
    unsigned u = __builtin_bit_cast(unsigned, f);
    u += 0x7fffu + ((u >> 16) & 1u);   // round-to-nearest-even
    return (short)(u >> 16);
}
static __device__ __forceinline__ float bf2f(short s) {
    unsigned u = ((unsigned)(unsigned short)s) << 16;
    return __builtin_bit_cast(float, u);
}
static __device__ __forceinline__ f32x4 ntl(const float* p) {
    return __builtin_nontemporal_load((const f32x4*)p);
}
static __device__ __forceinline__ void nts(float* p, f32x4 v) {
    __builtin_nontemporal_store(v, (f32x4*)p);
}

// ---------------------------------------------------------------- prep ----
// R23: single small kernel replaces k_init + k_scatter. The inv/mask fill is
// done by hipMemsetAsync (0xFF -> -1 int / 0x00 -> 0 byte) at fill rate.
// 512 blocks x 256 thr = 131072 threads: scatter (i < BATCH) + W bf16
// conversion (i < 98304) in one dispatch.
__global__ void k_prep(int* __restrict__ inv,            // may be null
                       unsigned char* __restrict__ mask, // may be null
                       const int* __restrict__ idx,
                       const float* __restrict__ Wih,
                       const float* __restrict__ Whh,
                       short* __restrict__ WbIH,
                       short* __restrict__ WbHH) {
    int i = blockIdx.x * blockDim.x + threadIdx.x;
    if (i < BATCH) {
        int n = idx[i];
        if (inv)  inv[n] = i;
        if (mask) mask[n] = 1;
    }
    if (i < 3 * DIM * DIM) {
        WbIH[i] = f2bf(Wih[i]);
        WbHH[i] = f2bf(Whh[i]);
    }
}

// --------------------------------------------------------------- stream ----
// FINAL = R16 (best of 22 measured variants, 248.0 us): inverse-index merged
// streaming kernel; scattered coprime block permutation (x4099 % 15625) for
// update/copy interleave; 32-row/8-wave tiles; th-outer MFMA (16 live acc
// regs); bf16 LDS tiles w/ Hn overlay; nontemporal streaming policy;
// vectorized LDS-staged epilogue. Verified-regressing alternatives: barrier
// removal (+30), 64-row tiles (+37), front-loaded regs (+45), forced
// occupancy (+164), superblocks (+60), chunked map (+216).
__global__ void __launch_bounds__(512)
k_stream(const float* __restrict__ hidden,
         const float* __restrict__ variance,
         const int*   __restrict__ inv,
         const float* __restrict__ xg,
         const short* __restrict__ WbIH,     // [384][128] bf16 bits
         const short* __restrict__ WbHH,
         const float* __restrict__ b_ih,
         const float* __restrict__ b_hh,
         float* __restrict__ out0,
         float* __restrict__ out1) {
    __shared__ __align__(16) char smem[26112];
    short (*Xb)[136] = (short(*)[136])smem;             // bf16 x tile
    short (*Hb)[136] = (short(*)[136])(smem + 8704);    // bf16 h tile
    short (*Vb)[136] = (short(*)[136])(smem + 17408);   // bf16 variance tile
    short (*Hn)[136] = (short(*)[136])smem;             // bf16 h_new, overlays Xb
    __shared__ int rinfo[32];
    __shared__ int hasUpd;

    const int t  = threadIdx.x;
    // bijective spread: 15625 = 5^6, gcd(4099,5)=1
    const int pb = (int)(((unsigned)blockIdx.x * 4099u) % 15625u);
    const int rb = pb * 32;

    if (t == 0) hasUpd = 0;
    if (t < 32) rinfo[t] = inv[rb + t];
    __syncthreads();
    if (t < 32 && rinfo[t] >= 0) hasUpd = 1;
    __syncthreads();

    if (!hasUpd) {
        // ---- pure copy: fully sequential streaming (nontemporal) ----
        #pragma unroll
        for (int jj = 0; jj < 2; ++jj) {
            int j = t + jj * 512;
            size_t off = (size_t)rb * DIM + j * 4;      // rows sequential
            f32x4 h = ntl(hidden + off);
            f32x4 v = ntl(variance + off);
            nts(out0 + off, h);
            nts(out1 + off, v);
        }
        return;
    }

    // ---- stage: local h/var + inv-gathered x; copy-out non-updated rows ----
    #pragma unroll
    for (int jj = 0; jj < 2; ++jj) {
        int j = t + jj * 512;
        int row = j >> 5, c4 = j & 31;
        size_t off = (size_t)(rb + row) * DIM + c4 * 4;
        f32x4 hv = ntl(hidden + off);
        f32x4 vv = ntl(variance + off);
        int iv = rinfo[row];
        f32x4 xv = {0.f, 0.f, 0.f, 0.f};
        if (iv >= 0) {
            xv = ntl(xg + (size_t)iv * DIM + c4 * 4);
        } else {
            nts(out0 + off, hv);                        // mixed block: copy now
            nts(out1 + off, vv);
        }
        short4_t xs, hs, vs;
        xs.x = f2bf(xv.x); xs.y = f2bf(xv.y); xs.z = f2bf(xv.z); xs.w = f2bf(xv.w);
        hs.x = f2bf(hv.x); hs.y = f2bf(hv.y); hs.z = f2bf(hv.z); hs.w = f2bf(hv.w);
        vs.x = f2bf(vv.x); vs.y = f2bf(vv.y); vs.z = f2bf(vv.z); vs.w = f2bf(vv.w);
        *(short4_t*)&Xb[row][c4 * 4] = xs;
        *(short4_t*)&Hb[row][c4 * 4] = hs;
        *(short4_t*)&Vb[row][c4 * 4] = vs;
    }
    __syncthreads();

    const int w  = t >> 6;       // wave id 0..7 -> output dims 16w..16w+15
    const int l  = t & 63;
    const int c  = l & 15;
    const int gq = l >> 4;

    // th-outer: per-third partial results held as scalars (32 f32)
    float sr[2][4], sz[2][4], gin[2][4], ghn[2][4];

    #pragma unroll
    for (int th = 0; th < 3; ++th) {
        f32x4 acc[2][2] = {};    // [m-tile][0=x@Wih 1=h@Whh] -- 16 live regs
        const int o = w * 16 + th * 128 + c;            // gate output row of W
        #pragma unroll
        for (int ks = 0; ks < 4; ++ks) {
            const int k0 = ks * 32 + gq * 8;
            const short8 aX0 = *(const short8*)&Xb[c][k0];
            const short8 aX1 = *(const short8*)&Xb[16 + c][k0];
            const short8 aH0 = *(const short8*)&Hb[c][k0];
            const short8 aH1 = *(const short8*)&Hb[16 + c][k0];
            const short8 bi = *(const short8*)(WbIH + (size_t)o * DIM + k0);
            const short8 bh = *(const short8*)(WbHH + (size_t)o * DIM + k0);
            acc[0][0] = __builtin_amdgcn_mfma_f32_16x16x32_bf16(aX0, bi, acc[0][0], 0, 0, 0);
            acc[1][0] = __builtin_amdgcn_mfma_f32_16x16x32_bf16(aX1, bi, acc[1][0], 0, 0, 0);
            acc[0][1] = __builtin_amdgcn_mfma_f32_16x16x32_bf16(aH0, bh, acc[0][1], 0, 0, 0);
            acc[1][1] = __builtin_amdgcn_mfma_f32_16x16x32_bf16(aH1, bh, acc[1][1], 0, 0, 0);
        }
        #pragma unroll
        for (int mt = 0; mt < 2; ++mt)
            #pragma unroll
            for (int r = 0; r < 4; ++r) {
                if (th == 0) sr[mt][r]  = acc[mt][0][r] + acc[mt][1][r];
                if (th == 1) sz[mt][r]  = acc[mt][0][r] + acc[mt][1][r];
                if (th == 2) { gin[mt][r] = acc[mt][0][r]; ghn[mt][r] = acc[mt][1][r]; }
            }
    }
    __syncthreads();   // Xb dead -> Hn overlay safe

    // ---- gate math; lane holds (m = mt*16 + gq*4 + r, d = 16w + c) ----
    const int d = w * 16 + c;
    const float bs_r = b_ih[d]       + b_hh[d];
    const float bs_z = b_ih[d + 128] + b_hh[d + 128];
    const float bi_n = b_ih[d + 256];
    const float bh_n = b_hh[d + 256];

    #pragma unroll
    for (int mt = 0; mt < 2; ++mt) {
        #pragma unroll
        for (int r = 0; r < 4; ++r) {
            const int m = mt * 16 + gq * 4 + r;
            float s_r  = sr[mt][r] + bs_r;
            float s_z  = sz[mt][r] + bs_z;
            float gi_n = gin[mt][r] + bi_n;
            float gh_n = ghn[mt][r] + bh_n;
            float rg = 1.f / (1.f + __expf(-s_r));
            float zg = 1.f / (1.f + __expf(-s_z));
            float aa = gi_n + rg * gh_n;
            float n  = 1.f - 2.f / (__expf(2.f * aa) + 1.f);   // tanh, inf-safe
            float h  = bf2f(Hb[m][d]);
            Hn[m][d] = f2bf((1.f - zg) * n + zg * h);
        }
    }
    __syncthreads();

    // ---- epilogue: LDS reads, sequential coalesced nontemporal stores ----
    #pragma unroll
    for (int jj = 0; jj < 2; ++jj) {
        int j = t + jj * 512;
        int row = j >> 5, c4 = j & 31;
        if (rinfo[row] < 0) continue;                  // copied at stage
        size_t off = (size_t)(rb + row) * DIM + c4 * 4;
        short4_t hns = *(short4_t*)&Hn[row][c4 * 4];
        short4_t hs  = *(short4_t*)&Hb[row][c4 * 4];
        short4_t vs  = *(short4_t*)&Vb[row][c4 * 4];
        f32x4 hn, var;
        hn.x = bf2f(hns.x); hn.y = bf2f(hns.y); hn.z = bf2f(hns.z); hn.w = bf2f(hns.w);
        float dx = hn.x - bf2f(hs.x), dy = hn.y - bf2f(hs.y);
        float dz = hn.z - bf2f(hs.z), dw = hn.w - bf2f(hs.w);
        var.x = 0.9f * bf2f(vs.x) + 0.1f * dx * dx;
        var.y = 0.9f * bf2f(vs.y) + 0.1f * dy * dy;
        var.z = 0.9f * bf2f(vs.z) + 0.1f * dz * dz;
        var.w = 0.9f * bf2f(vs.w) + 0.1f * dw * dw;
        nts(out0 + off, hn);
        nts(out1 + off, var);
    }
}

// ----------------------------------------------- fallback: R5 structure ----
__global__ void __launch_bounds__(256)
k_copy(const float* __restrict__ hidden,
       const float* __restrict__ variance,
       const unsigned char* __restrict__ mask,   // null -> copy all
       float* __restrict__ out0,
       float* __restrict__ out1) {
    int gid = blockIdx.x * 256 + threadIdx.x;
    int row = gid >> 4;
    int c8  = gid & 15;
    if (mask && mask[row]) return;
    size_t off = (size_t)row * DIM + c8 * 8;
    f32x4 a0 = *(const f32x4*)(hidden + off);
    f32x4 a1 = *(const f32x4*)(hidden + off + 4);
    f32x4 b0 = *(const f32x4*)(variance + off);
    f32x4 b1 = *(const f32x4*)(variance + off + 4);
    *(f32x4*)(out0 + off)     = a0;
    *(f32x4*)(out0 + off + 4) = a1;
    *(f32x4*)(out1 + off)     = b0;
    *(f32x4*)(out1 + off + 4) = b1;
}

__global__ void __launch_bounds__(512)
k_gru(const float* __restrict__ hidden,
      const float* __restrict__ variance,
      const int*   __restrict__ idx,
      const float* __restrict__ xg,
      const short* __restrict__ WbIH,
      const short* __restrict__ WbHH,
      const float* __restrict__ b_ih,
      const float* __restrict__ b_hh,
      float* __restrict__ out0,
      float* __restrict__ out1) {
    __shared__ __align__(16) char smem[26112];
    short (*Xb)[136] = (short(*)[136])smem;
    short (*Hb)[136] = (short(*)[136])(smem + 8704);
    short (*Vb)[136] = (short(*)[136])(smem + 17408);
    short (*Hn)[136] = (short(*)[136])smem;

    const int t  = threadIdx.x;
    const int rb = blockIdx.x * 32;

    #pragma unroll
    for (int jj = 0; jj < 2; ++jj) {
        int j = t + jj * 512;
        int row = j >> 5, c4 = j & 31;
        int node = idx[rb + row];
        f32x4 xv = *(const f32x4*)(xg + (size_t)(rb + row) * DIM + c4 * 4);
        f32x4 hv = *(const f32x4*)(hidden + (size_t)node * DIM + c4 * 4);
        f32x4 vv = *(const f32x4*)(variance + (size_t)node * DIM + c4 * 4);
        short4_t xs, hs, vs;
        xs.x = f2bf(xv.x); xs.y = f2bf(xv.y); xs.z = f2bf(xv.z); xs.w = f2bf(xv.w);
        hs.x = f2bf(hv.x); hs.y = f2bf(hv.y); hs.z = f2bf(hv.z); hs.w = f2bf(hv.w);
        vs.x = f2bf(vv.x); vs.y = f2bf(vv.y); vs.z = f2bf(vv.z); vs.w = f2bf(vv.w);
        *(short4_t*)&Xb[row][c4 * 4] = xs;
        *(short4_t*)&Hb[row][c4 * 4] = hs;
        *(short4_t*)&Vb[row][c4 * 4] = vs;
    }
    __syncthreads();

    const int w  = t >> 6;
    const int l  = t & 63;
    const int c  = l & 15;
    const int gq = l >> 4;

    f32x4 acc[2][3][2] = {};
    #pragma unroll
    for (int ks = 0; ks < 4; ++ks) {
        const int k0 = ks * 32 + gq * 8;
        short8 a[2][2];
        a[0][0] = *(const short8*)&Xb[c][k0];
        a[1][0] = *(const short8*)&Xb[16 + c][k0];
        a[0][1] = *(const short8*)&Hb[c][k0];
        a[1][1] = *(const short8*)&Hb[16 + c][k0];
        #pragma unroll
        for (int th = 0; th < 3; ++th) {
            const int o = w * 16 + th * 128 + c;
            const short8 bi = *(const short8*)(WbIH + (size_t)o * DIM + k0);
            const short8 bh = *(const short8*)(WbHH + (size_t)o * DIM + k0);
            #pragma unroll
            for (int mt = 0; mt < 2; ++mt) {
                acc[mt][th][0] = __builtin_amdgcn_mfma_f32_16x16x32_bf16(a[mt][0], bi, acc[mt][th][0], 0, 0, 0);
                acc[mt][th][1] = __builtin_amdgcn_mfma_f32_16x16x32_bf16(a[mt][1], bh, acc[mt][th][1], 0, 0, 0);
            }
        }
    }
    __syncthreads();

    const int d = w * 16 + c;
    const float bs_r = b_ih[d]       + b_hh[d];
    const float bs_z = b_ih[d + 128] + b_hh[d + 128];
    const float bi_n = b_ih[d + 256];
    const float bh_n = b_hh[d + 256];
    #pragma unroll
    for (int mt = 0; mt < 2; ++mt) {
        #pragma unroll
        for (int r = 0; r < 4; ++r) {
            const int m = mt * 16 + gq * 4 + r;
            float s_r  = acc[mt][0][0][r] + acc[mt][0][1][r] + bs_r;
            float s_z  = acc[mt][1][0][r] + acc[mt][1][1][r] + bs_z;
            float gi_n = acc[mt][2][0][r] + bi_n;
            float gh_n = acc[mt][2][1][r] + bh_n;
            float rg = 1.f / (1.f + __expf(-s_r));
            float zg = 1.f / (1.f + __expf(-s_z));
            float aa = gi_n + rg * gh_n;
            float n  = 1.f - 2.f / (__expf(2.f * aa) + 1.f);
            float h  = bf2f(Hb[m][d]);
            Hn[m][d] = f2bf((1.f - zg) * n + zg * h);
        }
    }
    __syncthreads();

    #pragma unroll
    for (int jj = 0; jj < 2; ++jj) {
        int j = t + jj * 512;
        int row = j >> 5, c4 = j & 31;
        int node = idx[rb + row];
        size_t off = (size_t)node * DIM + c4 * 4;
        short4_t hns = *(short4_t*)&Hn[row][c4 * 4];
        short4_t hs  = *(short4_t*)&Hb[row][c4 * 4];
        short4_t vs  = *(short4_t*)&Vb[row][c4 * 4];
        f32x4 hn, var;
        hn.x = bf2f(hns.x); hn.y = bf2f(hns.y); hn.z = bf2f(hns.z); hn.w = bf2f(hns.w);
        float dx = hn.x - bf2f(hs.x), dy = hn.y - bf2f(hs.y);
        float dz = hn.z - bf2f(hs.z), dw = hn.w - bf2f(hs.w);
        var.x = 0.9f * bf2f(vs.x) + 0.1f * dx * dx;
        var.y = 0.9f * bf2f(vs.y) + 0.1f * dy * dy;
        var.z = 0.9f * bf2f(vs.z) + 0.1f * dz * dz;
        var.w = 0.9f * bf2f(vs.w) + 0.1f * dw * dw;
        *(f32x4*)(out0 + off) = hn;
        *(f32x4*)(out1 + off) = var;
    }
}

// -------------------------------------------------------------- launch ----
extern "C" void kernel_launch(void* const* d_in, const int* in_sizes, int n_in,
                              void* d_out, int out_size, void* d_ws, size_t ws_size,
                              hipStream_t stream) {
    const float* hidden   = (const float*)d_in[0];
    const float* variance = (const float*)d_in[1];
    const int*   idx      = (const int*)d_in[2];
    const float* x        = (const float*)d_in[3];
    const float* Wih      = (const float*)d_in[4];
    const float* Whh      = (const float*)d_in[5];
    const float* bih      = (const float*)d_in[6];
    const float* bhh      = (const float*)d_in[7];
    float* out0 = (float*)d_out;
    float* out1 = out0 + (size_t)NUM_NODES * DIM;

    const size_t invB  = (size_t)NUM_NODES * 4;          // 2,000,000
    const size_t maskB = (size_t)NUM_NODES;              // 500,000
    const size_t wB    = (size_t)3 * DIM * DIM * 2;      // 196,608 per matrix

    const bool full = ws_size >= invB + 2 * wB;          // streaming path
    const bool mid  = !full && ws_size >= maskB + 16 + 2 * wB;

    if (full) {
        int*   inv  = (int*)d_ws;
        short* WbIH = (short*)((char*)d_ws + invB);      // invB % 16 == 0
        short* WbHH = WbIH + 3 * DIM * DIM;
        hipMemsetAsync(inv, 0xFF, invB, stream);         // inv[i] = -1, fill rate
        k_prep<<<(BATCH + 255) / 256, 256, 0, stream>>>(
            inv, nullptr, idx, Wih, Whh, WbIH, WbHH);
        k_stream<<<NBLK, 512, 0, stream>>>(hidden, variance, inv, x,
                                           WbIH, WbHH, bih, bhh, out0, out1);
    } else if (mid) {
        unsigned char* mask = (unsigned char*)d_ws;
        short* WbIH = (short*)((char*)d_ws + ((maskB + 15) & ~size_t(15)));
        short* WbHH = WbIH + 3 * DIM * DIM;
        hipMemsetAsync(mask, 0x00, maskB, stream);       // mask[i] = 0
        k_prep<<<(BATCH + 255) / 256, 256, 0, stream>>>(
            nullptr, mask, idx, Wih, Whh, WbIH, WbHH);
        k_copy<<<(NUM_NODES * 16) / 256, 256, 0, stream>>>(
            hidden, variance, mask, out0, out1);
        k_gru<<<BATCH / 32, 512, 0, stream>>>(hidden, variance, idx, x,
                                              WbIH, WbHH, bih, bhh, out0, out1);
    } else {
        short* WbIH = (short*)d_ws;
        short* WbHH = WbIH + 3 * DIM * DIM;
        k_prep<<<(BATCH + 255) / 256, 256, 0, stream>>>(
            nullptr, nullptr, idx, Wih, Whh, WbIH, WbHH);
        k_copy<<<(NUM_NODES * 16) / 256, 256, 0, stream>>>(
            hidden, variance, nullptr, out0, out1);
        k_gru<<<BATCH / 32, 512, 0, stream>>>(hidden, variance, idx, x,
                                              WbIH, WbHH, bih, bhh, out0, out1);
    }
}

// Round 24
// 247.885 us; speedup vs baseline: 1.0134x; 1.0134x over previous
//
#include <hip/hip_runtime.h>
#include <hip/hip_bf16.h>
#include <cstdint>
#include <cstddef>

#define NUM_NODES 500000
#define DIM 128
#define BATCH 131072
#define NBLK (NUM_NODES / 32)     // 15625 exactly

typedef __attribute__((ext_vector_type(8))) short short8;
typedef __attribute__((ext_vector_type(4))) short short4_t;
typedef __attribute__((ext_vector_type(4))) float f32x4;

static __device__ __forceinline__ short f2bf(float f) {
    unsigned u = __builtin_bit_cast(unsigned, f);
    u += 0x7fffu + ((u >> 16) & 1u);   // round-to-nearest-even
    return (short)(u >> 16);
}
static __device__ __forceinline__ float bf2f(short s) {
    unsigned u = ((unsigned)(unsigned short)s) << 16;
    return __builtin_bit_cast(float, u);
}
static __device__ __forceinline__ f32x4 ntl(const float* p) {
    return __builtin_nontemporal_load((const f32x4*)p);
}
static __device__ __forceinline__ void nts(float* p, f32x4 v) {
    __builtin_nontemporal_store(v, (f32x4*)p);
}

// ---------------------------------------------------------------- init ----
__global__ void k_init(int* __restrict__ inv,            // may be null
                       unsigned char* __restrict__ mask, // may be null
                       const float* __restrict__ Wih,
                       const float* __restrict__ Whh,
                       short* __restrict__ WbIH,
                       short* __restrict__ WbHH) {
    int i = blockIdx.x * blockDim.x + threadIdx.x;
    if (i < NUM_NODES) {
        if (inv)  inv[i] = -1;
        if (mask) mask[i] = 0;
    }
    if (i < 3 * DIM * DIM) {
        WbIH[i] = f2bf(Wih[i]);
        WbHH[i] = f2bf(Whh[i]);
    }
}

__global__ void k_scatter(int* __restrict__ inv, unsigned char* __restrict__ mask,
                          const int* __restrict__ idx) {
    int i = blockIdx.x * blockDim.x + threadIdx.x;
    if (i < BATCH) {
        int n = idx[i];
        if (inv)  inv[n] = i;
        if (mask) mask[n] = 1;
    }
}

// --------------------------------------------------------------- stream ----
// FINAL champion (248.0 us, best of 23 measured rounds): inverse-index merged
// streaming kernel; scattered coprime block permutation (x4099 % 15625) for
// update/copy interleave; 32-row/8-wave tiles; th-outer MFMA (16 live acc
// regs); bf16 LDS tiles w/ Hn overlay; nontemporal streaming policy;
// vectorized LDS-staged epilogue.
__global__ void __launch_bounds__(512)
k_stream(const float* __restrict__ hidden,
         const float* __restrict__ variance,
         const int*   __restrict__ inv,
         const float* __restrict__ xg,
         const short* __restrict__ WbIH,     // [384][128] bf16 bits
         const short* __restrict__ WbHH,
         const float* __restrict__ b_ih,
         const float* __restrict__ b_hh,
         float* __restrict__ out0,
         float* __restrict__ out1) {
    __shared__ __align__(16) char smem[26112];
    short (*Xb)[136] = (short(*)[136])smem;             // bf16 x tile
    short (*Hb)[136] = (short(*)[136])(smem + 8704);    // bf16 h tile
    short (*Vb)[136] = (short(*)[136])(smem + 17408);   // bf16 variance tile
    short (*Hn)[136] = (short(*)[136])smem;             // bf16 h_new, overlays Xb
    __shared__ int rinfo[32];
    __shared__ int hasUpd;

    const int t  = threadIdx.x;
    // bijective spread: 15625 = 5^6, gcd(4099,5)=1
    const int pb = (int)(((unsigned)blockIdx.x * 4099u) % 15625u);
    const int rb = pb * 32;

    if (t == 0) hasUpd = 0;
    if (t < 32) rinfo[t] = inv[rb + t];
    __syncthreads();
    if (t < 32 && rinfo[t] >= 0) hasUpd = 1;
    __syncthreads();

    if (!hasUpd) {
        // ---- pure copy: fully sequential streaming (nontemporal) ----
        #pragma unroll
        for (int jj = 0; jj < 2; ++jj) {
            int j = t + jj * 512;
            size_t off = (size_t)rb * DIM + j * 4;      // rows sequential
            f32x4 h = ntl(hidden + off);
            f32x4 v = ntl(variance + off);
            nts(out0 + off, h);
            nts(out1 + off, v);
        }
        return;
    }

    // ---- stage: local h/var + inv-gathered x; copy-out non-updated rows ----
    #pragma unroll
    for (int jj = 0; jj < 2; ++jj) {
        int j = t + jj * 512;
        int row = j >> 5, c4 = j & 31;
        size_t off = (size_t)(rb + row) * DIM + c4 * 4;
        f32x4 hv = ntl(hidden + off);
        f32x4 vv = ntl(variance + off);
        int iv = rinfo[row];
        f32x4 xv = {0.f, 0.f, 0.f, 0.f};
        if (iv >= 0) {
            xv = ntl(xg + (size_t)iv * DIM + c4 * 4);
        } else {
            nts(out0 + off, hv);                        // mixed block: copy now
            nts(out1 + off, vv);
        }
        short4_t xs, hs, vs;
        xs.x = f2bf(xv.x); xs.y = f2bf(xv.y); xs.z = f2bf(xv.z); xs.w = f2bf(xv.w);
        hs.x = f2bf(hv.x); hs.y = f2bf(hv.y); hs.z = f2bf(hv.z); hs.w = f2bf(hv.w);
        vs.x = f2bf(vv.x); vs.y = f2bf(vv.y); vs.z = f2bf(vv.z); vs.w = f2bf(vv.w);
        *(short4_t*)&Xb[row][c4 * 4] = xs;
        *(short4_t*)&Hb[row][c4 * 4] = hs;
        *(short4_t*)&Vb[row][c4 * 4] = vs;
    }
    __syncthreads();

    const int w  = t >> 6;       // wave id 0..7 -> output dims 16w..16w+15
    const int l  = t & 63;
    const int c  = l & 15;
    const int gq = l >> 4;

    // th-outer: per-third partial results held as scalars (32 f32)
    float sr[2][4], sz[2][4], gin[2][4], ghn[2][4];

    #pragma unroll
    for (int th = 0; th < 3; ++th) {
        f32x4 acc[2][2] = {};    // [m-tile][0=x@Wih 1=h@Whh] -- 16 live regs
        const int o = w * 16 + th * 128 + c;            // gate output row of W
        #pragma unroll
        for (int ks = 0; ks < 4; ++ks) {
            const int k0 = ks * 32 + gq * 8;
            const short8 aX0 = *(const short8*)&Xb[c][k0];
            const short8 aX1 = *(const short8*)&Xb[16 + c][k0];
            const short8 aH0 = *(const short8*)&Hb[c][k0];
            const short8 aH1 = *(const short8*)&Hb[16 + c][k0];
            const short8 bi = *(const short8*)(WbIH + (size_t)o * DIM + k0);
            const short8 bh = *(const short8*)(WbHH + (size_t)o * DIM + k0);
            acc[0][0] = __builtin_amdgcn_mfma_f32_16x16x32_bf16(aX0, bi, acc[0][0], 0, 0, 0);
            acc[1][0] = __builtin_amdgcn_mfma_f32_16x16x32_bf16(aX1, bi, acc[1][0], 0, 0, 0);
            acc[0][1] = __builtin_amdgcn_mfma_f32_16x16x32_bf16(aH0, bh, acc[0][1], 0, 0, 0);
            acc[1][1] = __builtin_amdgcn_mfma_f32_16x16x32_bf16(aH1, bh, acc[1][1], 0, 0, 0);
        }
        #pragma unroll
        for (int mt = 0; mt < 2; ++mt)
            #pragma unroll
            for (int r = 0; r < 4; ++r) {
                if (th == 0) sr[mt][r]  = acc[mt][0][r] + acc[mt][1][r];
                if (th == 1) sz[mt][r]  = acc[mt][0][r] + acc[mt][1][r];
                if (th == 2) { gin[mt][r] = acc[mt][0][r]; ghn[mt][r] = acc[mt][1][r]; }
            }
    }
    __syncthreads();   // Xb dead -> Hn overlay safe

    // ---- gate math; lane holds (m = mt*16 + gq*4 + r, d = 16w + c) ----
    const int d = w * 16 + c;
    const float bs_r = b_ih[d]       + b_hh[d];
    const float bs_z = b_ih[d + 128] + b_hh[d + 128];
    const float bi_n = b_ih[d + 256];
    const float bh_n = b_hh[d + 256];

    #pragma unroll
    for (int mt = 0; mt < 2; ++mt) {
        #pragma unroll
        for (int r = 0; r < 4; ++r) {
            const int m = mt * 16 + gq * 4 + r;
            float s_r  = sr[mt][r] + bs_r;
            float s_z  = sz[mt][r] + bs_z;
            float gi_n = gin[mt][r] + bi_n;
            float gh_n = ghn[mt][r] + bh_n;
            float rg = 1.f / (1.f + __expf(-s_r));
            float zg = 1.f / (1.f + __expf(-s_z));
            float aa = gi_n + rg * gh_n;
            float n  = 1.f - 2.f / (__expf(2.f * aa) + 1.f);   // tanh, inf-safe
            float h  = bf2f(Hb[m][d]);
            Hn[m][d] = f2bf((1.f - zg) * n + zg * h);
        }
    }
    __syncthreads();

    // ---- epilogue: LDS reads, sequential coalesced nontemporal stores ----
    #pragma unroll
    for (int jj = 0; jj < 2; ++jj) {
        int j = t + jj * 512;
        int row = j >> 5, c4 = j & 31;
        if (rinfo[row] < 0) continue;                  // copied at stage
        size_t off = (size_t)(rb + row) * DIM + c4 * 4;
        short4_t hns = *(short4_t*)&Hn[row][c4 * 4];
        short4_t hs  = *(short4_t*)&Hb[row][c4 * 4];
        short4_t vs  = *(short4_t*)&Vb[row][c4 * 4];
        f32x4 hn, var;
        hn.x = bf2f(hns.x); hn.y = bf2f(hns.y); hn.z = bf2f(hns.z); hn.w = bf2f(hns.w);
        float dx = hn.x - bf2f(hs.x), dy = hn.y - bf2f(hs.y);
        float dz = hn.z - bf2f(hs.z), dw = hn.w - bf2f(hs.w);
        var.x = 0.9f * bf2f(vs.x) + 0.1f * dx * dx;
        var.y = 0.9f * bf2f(vs.y) + 0.1f * dy * dy;
        var.z = 0.9f * bf2f(vs.z) + 0.1f * dz * dz;
        var.w = 0.9f * bf2f(vs.w) + 0.1f * dw * dw;
        nts(out0 + off, hn);
        nts(out1 + off, var);
    }
}

// ----------------------------------------------- fallback: R5 structure ----
__global__ void __launch_bounds__(256)
k_copy(const float* __restrict__ hidden,
       const float* __restrict__ variance,
       const unsigned char* __restrict__ mask,   // null -> copy all
       float* __restrict__ out0,
       float* __restrict__ out1) {
    int gid = blockIdx.x * 256 + threadIdx.x;
    int row = gid >> 4;
    int c8  = gid & 15;
    if (mask && mask[row]) return;
    size_t off = (size_t)row * DIM + c8 * 8;
    f32x4 a0 = *(const f32x4*)(hidden + off);
    f32x4 a1 = *(const f32x4*)(hidden + off + 4);
    f32x4 b0 = *(const f32x4*)(variance + off);
    f32x4 b1 = *(const f32x4*)(variance + off + 4);
    *(f32x4*)(out0 + off)     = a0;
    *(f32x4*)(out0 + off + 4) = a1;
    *(f32x4*)(out1 + off)     = b0;
    *(f32x4*)(out1 + off + 4) = b1;
}

__global__ void __launch_bounds__(512)
k_gru(const float* __restrict__ hidden,
      const float* __restrict__ variance,
      const int*   __restrict__ idx,
      const float* __restrict__ xg,
      const short* __restrict__ WbIH,
      const short* __restrict__ WbHH,
      const float* __restrict__ b_ih,
      const float* __restrict__ b_hh,
      float* __restrict__ out0,
      float* __restrict__ out1) {
    __shared__ __align__(16) char smem[26112];
    short (*Xb)[136] = (short(*)[136])smem;
    short (*Hb)[136] = (short(*)[136])(smem + 8704);
    short (*Vb)[136] = (short(*)[136])(smem + 17408);
    short (*Hn)[136] = (short(*)[136])smem;

    const int t  = threadIdx.x;
    const int rb = blockIdx.x * 32;

    #pragma unroll
    for (int jj = 0; jj < 2; ++jj) {
        int j = t + jj * 512;
        int row = j >> 5, c4 = j & 31;
        int node = idx[rb + row];
        f32x4 xv = *(const f32x4*)(xg + (size_t)(rb + row) * DIM + c4 * 4);
        f32x4 hv = *(const f32x4*)(hidden + (size_t)node * DIM + c4 * 4);
        f32x4 vv = *(const f32x4*)(variance + (size_t)node * DIM + c4 * 4);
        short4_t xs, hs, vs;
        xs.x = f2bf(xv.x); xs.y = f2bf(xv.y); xs.z = f2bf(xv.z); xs.w = f2bf(xv.w);
        hs.x = f2bf(hv.x); hs.y = f2bf(hv.y); hs.z = f2bf(hv.z); hs.w = f2bf(hv.w);
        vs.x = f2bf(vv.x); vs.y = f2bf(vv.y); vs.z = f2bf(vv.z); vs.w = f2bf(vv.w);
        *(short4_t*)&Xb[row][c4 * 4] = xs;
        *(short4_t*)&Hb[row][c4 * 4] = hs;
        *(short4_t*)&Vb[row][c4 * 4] = vs;
    }
    __syncthreads();

    const int w  = t >> 6;
    const int l  = t & 63;
    const int c  = l & 15;
    const int gq = l >> 4;

    f32x4 acc[2][3][2] = {};
    #pragma unroll
    for (int ks = 0; ks < 4; ++ks) {
        const int k0 = ks * 32 + gq * 8;
        short8 a[2][2];
        a[0][0] = *(const short8*)&Xb[c][k0];
        a[1][0] = *(const short8*)&Xb[16 + c][k0];
        a[0][1] = *(const short8*)&Hb[c][k0];
        a[1][1] = *(const short8*)&Hb[16 + c][k0];
        #pragma unroll
        for (int th = 0; th < 3; ++th) {
            const int o = w * 16 + th * 128 + c;
            const short8 bi = *(const short8*)(WbIH + (size_t)o * DIM + k0);
            const short8 bh = *(const short8*)(WbHH + (size_t)o * DIM + k0);
            #pragma unroll
            for (int mt = 0; mt < 2; ++mt) {
                acc[mt][th][0] = __builtin_amdgcn_mfma_f32_16x16x32_bf16(a[mt][0], bi, acc[mt][th][0], 0, 0, 0);
                acc[mt][th][1] = __builtin_amdgcn_mfma_f32_16x16x32_bf16(a[mt][1], bh, acc[mt][th][1], 0, 0, 0);
            }
        }
    }
    __syncthreads();

    const int d = w * 16 + c;
    const float bs_r = b_ih[d]       + b_hh[d];
    const float bs_z = b_ih[d + 128] + b_hh[d + 128];
    const float bi_n = b_ih[d + 256];
    const float bh_n = b_hh[d + 256];
    #pragma unroll
    for (int mt = 0; mt < 2; ++mt) {
        #pragma unroll
        for (int r = 0; r < 4; ++r) {
            const int m = mt * 16 + gq * 4 + r;
            float s_r  = acc[mt][0][0][r] + acc[mt][0][1][r] + bs_r;
            float s_z  = acc[mt][1][0][r] + acc[mt][1][1][r] + bs_z;
            float gi_n = acc[mt][2][0][r] + bi_n;
            float gh_n = acc[mt][2][1][r] + bh_n;
            float rg = 1.f / (1.f + __expf(-s_r));
            float zg = 1.f / (1.f + __expf(-s_z));
            float aa = gi_n + rg * gh_n;
            float n  = 1.f - 2.f / (__expf(2.f * aa) + 1.f);
            float h  = bf2f(Hb[m][d]);
            Hn[m][d] = f2bf((1.f - zg) * n + zg * h);
        }
    }
    __syncthreads();

    #pragma unroll
    for (int jj = 0; jj < 2; ++jj) {
        int j = t + jj * 512;
        int row = j >> 5, c4 = j & 31;
        int node = idx[rb + row];
        size_t off = (size_t)node * DIM + c4 * 4;
        short4_t hns = *(short4_t*)&Hn[row][c4 * 4];
        short4_t hs  = *(short4_t*)&Hb[row][c4 * 4];
        short4_t vs  = *(short4_t*)&Vb[row][c4 * 4];
        f32x4 hn, var;
        hn.x = bf2f(hns.x); hn.y = bf2f(hns.y); hn.z = bf2f(hns.z); hn.w = bf2f(hns.w);
        float dx = hn.x - bf2f(hs.x), dy = hn.y - bf2f(hs.y);
        float dz = hn.z - bf2f(hs.z), dw = hn.w - bf2f(hs.w);
        var.x = 0.9f * bf2f(vs.x) + 0.1f * dx * dx;
        var.y = 0.9f * bf2f(vs.y) + 0.1f * dy * dy;
        var.z = 0.9f * bf2f(vs.z) + 0.1f * dz * dz;
        var.w = 0.9f * bf2f(vs.w) + 0.1f * dw * dw;
        *(f32x4*)(out0 + off) = hn;
        *(f32x4*)(out1 + off) = var;
    }
}

// -------------------------------------------------------------- launch ----
extern "C" void kernel_launch(void* const* d_in, const int* in_sizes, int n_in,
                              void* d_out, int out_size, void* d_ws, size_t ws_size,
                              hipStream_t stream) {
    const float* hidden   = (const float*)d_in[0];
    const float* variance = (const float*)d_in[1];
    const int*   idx      = (const int*)d_in[2];
    const float* x        = (const float*)d_in[3];
    const float* Wih      = (const float*)d_in[4];
    const float* Whh      = (const float*)d_in[5];
    const float* bih      = (const float*)d_in[6];
    const float* bhh      = (const float*)d_in[7];
    float* out0 = (float*)d_out;
    float* out1 = out0 + (size_t)NUM_NODES * DIM;

    const size_t invB  = (size_t)NUM_NODES * 4;          // 2,000,000
    const size_t maskB = (size_t)NUM_NODES;              // 500,000
    const size_t wB    = (size_t)3 * DIM * DIM * 2;      // 196,608 per matrix

    const bool full = ws_size >= invB + 2 * wB;          // streaming path
    const bool mid  = !full && ws_size >= maskB + 16 + 2 * wB;

    if (full) {
        int*   inv  = (int*)d_ws;
        short* WbIH = (short*)((char*)d_ws + invB);      // invB % 16 == 0
        short* WbHH = WbIH + 3 * DIM * DIM;
        k_init<<<(NUM_NODES + 255) / 256, 256, 0, stream>>>(
            inv, nullptr, Wih, Whh, WbIH, WbHH);
        k_scatter<<<BATCH / 256, 256, 0, stream>>>(inv, nullptr, idx);
        k_stream<<<NBLK, 512, 0, stream>>>(hidden, variance, inv, x,
                                           WbIH, WbHH, bih, bhh, out0, out1);
    } else if (mid) {
        unsigned char* mask = (unsigned char*)d_ws;
        short* WbIH = (short*)((char*)d_ws + ((maskB + 15) & ~size_t(15)));
        short* WbHH = WbIH + 3 * DIM * DIM;
        k_init<<<(NUM_NODES + 255) / 256, 256, 0, stream>>>(
            nullptr, mask, Wih, Whh, WbIH, WbHH);
        k_scatter<<<BATCH / 256, 256, 0, stream>>>(nullptr, mask, idx);
        k_copy<<<(NUM_NODES * 16) / 256, 256, 0, stream>>>(
            hidden, variance, mask, out0, out1);
        k_gru<<<BATCH / 32, 512, 0, stream>>>(hidden, variance, idx, x,
                                              WbIH, WbHH, bih, bhh, out0, out1);
    } else {
        short* WbIH = (short*)d_ws;
        short* WbHH = WbIH + 3 * DIM * DIM;
        k_init<<<(NUM_NODES + 255) / 256, 256, 0, stream>>>(
            nullptr, nullptr, Wih, Whh, WbIH, WbHH);
        k_copy<<<(NUM_NODES * 16) / 256, 256, 0, stream>>>(
            hidden, variance, nullptr, out0, out1);
        k_gru<<<BATCH / 32, 512, 0, stream>>>(hidden, variance, idx, x,
                                              WbIH, WbHH, bih, bhh, out0, out1);
    }
}

// Round 25
// 247.374 us; speedup vs baseline: 1.0155x; 1.0021x over previous
//
#include <hip/hip_runtime.h>
#include <hip/hip_bf16.h>
#include <cstdint>
#include <cstddef>

#define NUM_NODES 500000
#define DIM 128
#define BATCH 131072
#define NBLK (NUM_NODES / 32)     // 15625 exactly

typedef __attribute__((ext_vector_type(8))) short short8;
typedef __attribute__((ext_vector_type(4))) short short4_t;
typedef __attribute__((ext_vector_type(4))) float f32x4;

static __device__ __forceinline__ short f2bf(float f) {
    unsigned u = __builtin_bit_cast(unsigned, f);
    u += 0x7fffu + ((u >> 16) & 1u);   // round-to-nearest-even
    return (short)(u >> 16);
}
static __device__ __forceinline__ float bf2f(short s) {
    unsigned u = ((unsigned)(unsigned short)s) << 16;
    return __builtin_bit_cast(float, u);
}
static __device__ __forceinline__ f32x4 ntl(const float* p) {
    return __builtin_nontemporal_load((const f32x4*)p);
}
static __device__ __forceinline__ void nts(float* p, f32x4 v) {
    __builtin_nontemporal_store(v, (f32x4*)p);
}

// ---------------------------------------------------------------- init ----
__global__ void k_init(int* __restrict__ inv,            // may be null
                       unsigned char* __restrict__ mask, // may be null
                       const float* __restrict__ Wih,
                       const float* __restrict__ Whh,
                       short* __restrict__ WbIH,
                       short* __restrict__ WbHH) {
    int i = blockIdx.x * blockDim.x + threadIdx.x;
    if (i < NUM_NODES) {
        if (inv)  inv[i] = -1;
        if (mask) mask[i] = 0;
    }
    if (i < 3 * DIM * DIM) {
        WbIH[i] = f2bf(Wih[i]);
        WbHH[i] = f2bf(Whh[i]);
    }
}

__global__ void k_scatter(int* __restrict__ inv, unsigned char* __restrict__ mask,
                          const int* __restrict__ idx) {
    int i = blockIdx.x * blockDim.x + threadIdx.x;
    if (i < BATCH) {
        int n = idx[i];
        if (inv)  inv[n] = i;
        if (mask) mask[n] = 1;
    }
}

// --------------------------------------------------------------- stream ----
// R25 vs champion (single variable): gate-reordered th-passes. Sigmoid applied
// INSIDE th=0/1 passes so only rg[2][4]+zg[2][4] (16 floats) stay live across
// passes instead of sr/sz/gin/ghn (32). th=2 consumes its accumulators in
// place (after an Xb-drain barrier) and writes Hn directly. Goal: VGPR <= 64
// organically -> 8 waves/SIMD -> 4 blocks/CU (vs 3 at ~72 VGPR).
// Everything else byte-identical to the 247.9-us champion.
__global__ void __launch_bounds__(512)
k_stream(const float* __restrict__ hidden,
         const float* __restrict__ variance,
         const int*   __restrict__ inv,
         const float* __restrict__ xg,
         const short* __restrict__ WbIH,     // [384][128] bf16 bits
         const short* __restrict__ WbHH,
         const float* __restrict__ b_ih,
         const float* __restrict__ b_hh,
         float* __restrict__ out0,
         float* __restrict__ out1) {
    __shared__ __align__(16) char smem[26112];
    short (*Xb)[136] = (short(*)[136])smem;             // bf16 x tile
    short (*Hb)[136] = (short(*)[136])(smem + 8704);    // bf16 h tile
    short (*Vb)[136] = (short(*)[136])(smem + 17408);   // bf16 variance tile
    short (*Hn)[136] = (short(*)[136])smem;             // bf16 h_new, overlays Xb
    __shared__ int rinfo[32];
    __shared__ int hasUpd;

    const int t  = threadIdx.x;
    // bijective spread: 15625 = 5^6, gcd(4099,5)=1
    const int pb = (int)(((unsigned)blockIdx.x * 4099u) % 15625u);
    const int rb = pb * 32;

    if (t == 0) hasUpd = 0;
    if (t < 32) rinfo[t] = inv[rb + t];
    __syncthreads();
    if (t < 32 && rinfo[t] >= 0) hasUpd = 1;
    __syncthreads();

    if (!hasUpd) {
        // ---- pure copy: fully sequential streaming (nontemporal) ----
        #pragma unroll
        for (int jj = 0; jj < 2; ++jj) {
            int j = t + jj * 512;
            size_t off = (size_t)rb * DIM + j * 4;      // rows sequential
            f32x4 h = ntl(hidden + off);
            f32x4 v = ntl(variance + off);
            nts(out0 + off, h);
            nts(out1 + off, v);
        }
        return;
    }

    // ---- stage: local h/var + inv-gathered x; copy-out non-updated rows ----
    #pragma unroll
    for (int jj = 0; jj < 2; ++jj) {
        int j = t + jj * 512;
        int row = j >> 5, c4 = j & 31;
        size_t off = (size_t)(rb + row) * DIM + c4 * 4;
        f32x4 hv = ntl(hidden + off);
        f32x4 vv = ntl(variance + off);
        int iv = rinfo[row];
        f32x4 xv = {0.f, 0.f, 0.f, 0.f};
        if (iv >= 0) {
            xv = ntl(xg + (size_t)iv * DIM + c4 * 4);
        } else {
            nts(out0 + off, hv);                        // mixed block: copy now
            nts(out1 + off, vv);
        }
        short4_t xs, hs, vs;
        xs.x = f2bf(xv.x); xs.y = f2bf(xv.y); xs.z = f2bf(xv.z); xs.w = f2bf(xv.w);
        hs.x = f2bf(hv.x); hs.y = f2bf(hv.y); hs.z = f2bf(hv.z); hs.w = f2bf(hv.w);
        vs.x = f2bf(vv.x); vs.y = f2bf(vv.y); vs.z = f2bf(vv.z); vs.w = f2bf(vv.w);
        *(short4_t*)&Xb[row][c4 * 4] = xs;
        *(short4_t*)&Hb[row][c4 * 4] = hs;
        *(short4_t*)&Vb[row][c4 * 4] = vs;
    }
    __syncthreads();

    const int w  = t >> 6;       // wave id 0..7 -> output dims 16w..16w+15
    const int l  = t & 63;
    const int c  = l & 15;
    const int gq = l >> 4;

    const int d = w * 16 + c;
    const float bs_r = b_ih[d]       + b_hh[d];
    const float bs_z = b_ih[d + 128] + b_hh[d + 128];
    const float bi_n = b_ih[d + 256];
    const float bh_n = b_hh[d + 256];

    // gate-reordered: only rg, zg live across passes (16 floats)
    float rg[2][4], zg[2][4];

    #pragma unroll
    for (int th = 0; th < 3; ++th) {
        f32x4 acc[2][2] = {};    // [m-tile][0=x@Wih 1=h@Whh] -- 16 live regs
        const int o = w * 16 + th * 128 + c;            // gate output row of W
        #pragma unroll
        for (int ks = 0; ks < 4; ++ks) {
            const int k0 = ks * 32 + gq * 8;
            const short8 aX0 = *(const short8*)&Xb[c][k0];
            const short8 aX1 = *(const short8*)&Xb[16 + c][k0];
            const short8 aH0 = *(const short8*)&Hb[c][k0];
            const short8 aH1 = *(const short8*)&Hb[16 + c][k0];
            const short8 bi = *(const short8*)(WbIH + (size_t)o * DIM + k0);
            const short8 bh = *(const short8*)(WbHH + (size_t)o * DIM + k0);
            acc[0][0] = __builtin_amdgcn_mfma_f32_16x16x32_bf16(aX0, bi, acc[0][0], 0, 0, 0);
            acc[1][0] = __builtin_amdgcn_mfma_f32_16x16x32_bf16(aX1, bi, acc[1][0], 0, 0, 0);
            acc[0][1] = __builtin_amdgcn_mfma_f32_16x16x32_bf16(aH0, bh, acc[0][1], 0, 0, 0);
            acc[1][1] = __builtin_amdgcn_mfma_f32_16x16x32_bf16(aH1, bh, acc[1][1], 0, 0, 0);
        }
        if (th == 0) {
            #pragma unroll
            for (int mt = 0; mt < 2; ++mt)
                #pragma unroll
                for (int r = 0; r < 4; ++r)
                    rg[mt][r] = 1.f / (1.f + __expf(-(acc[mt][0][r] + acc[mt][1][r] + bs_r)));
        } else if (th == 1) {
            #pragma unroll
            for (int mt = 0; mt < 2; ++mt)
                #pragma unroll
                for (int r = 0; r < 4; ++r)
                    zg[mt][r] = 1.f / (1.f + __expf(-(acc[mt][0][r] + acc[mt][1][r] + bs_z)));
        } else {
            __syncthreads();     // all waves done with Xb MFMA reads -> Hn ok
            #pragma unroll
            for (int mt = 0; mt < 2; ++mt) {
                #pragma unroll
                for (int r = 0; r < 4; ++r) {
                    const int m = mt * 16 + gq * 4 + r;
                    float aa = (acc[mt][0][r] + bi_n) + rg[mt][r] * (acc[mt][1][r] + bh_n);
                    float n  = 1.f - 2.f / (__expf(2.f * aa) + 1.f);   // tanh
                    float h  = bf2f(Hb[m][d]);
                    Hn[m][d] = f2bf((1.f - zg[mt][r]) * n + zg[mt][r] * h);
                }
            }
        }
    }
    __syncthreads();

    // ---- epilogue: LDS reads, sequential coalesced nontemporal stores ----
    #pragma unroll
    for (int jj = 0; jj < 2; ++jj) {
        int j = t + jj * 512;
        int row = j >> 5, c4 = j & 31;
        if (rinfo[row] < 0) continue;                  // copied at stage
        size_t off = (size_t)(rb + row) * DIM + c4 * 4;
        short4_t hns = *(short4_t*)&Hn[row][c4 * 4];
        short4_t hs  = *(short4_t*)&Hb[row][c4 * 4];
        short4_t vs  = *(short4_t*)&Vb[row][c4 * 4];
        f32x4 hn, var;
        hn.x = bf2f(hns.x); hn.y = bf2f(hns.y); hn.z = bf2f(hns.z); hn.w = bf2f(hns.w);
        float dx = hn.x - bf2f(hs.x), dy = hn.y - bf2f(hs.y);
        float dz = hn.z - bf2f(hs.z), dw = hn.w - bf2f(hs.w);
        var.x = 0.9f * bf2f(vs.x) + 0.1f * dx * dx;
        var.y = 0.9f * bf2f(vs.y) + 0.1f * dy * dy;
        var.z = 0.9f * bf2f(vs.z) + 0.1f * dz * dz;
        var.w = 0.9f * bf2f(vs.w) + 0.1f * dw * dw;
        nts(out0 + off, hn);
        nts(out1 + off, var);
    }
}

// ----------------------------------------------- fallback: R5 structure ----
__global__ void __launch_bounds__(256)
k_copy(const float* __restrict__ hidden,
       const float* __restrict__ variance,
       const unsigned char* __restrict__ mask,   // null -> copy all
       float* __restrict__ out0,
       float* __restrict__ out1) {
    int gid = blockIdx.x * 256 + threadIdx.x;
    int row = gid >> 4;
    int c8  = gid & 15;
    if (mask && mask[row]) return;
    size_t off = (size_t)row * DIM + c8 * 8;
    f32x4 a0 = *(const f32x4*)(hidden + off);
    f32x4 a1 = *(const f32x4*)(hidden + off + 4);
    f32x4 b0 = *(const f32x4*)(variance + off);
    f32x4 b1 = *(const f32x4*)(variance + off + 4);
    *(f32x4*)(out0 + off)     = a0;
    *(f32x4*)(out0 + off + 4) = a1;
    *(f32x4*)(out1 + off)     = b0;
    *(f32x4*)(out1 + off + 4) = b1;
}

__global__ void __launch_bounds__(512)
k_gru(const float* __restrict__ hidden,
      const float* __restrict__ variance,
      const int*   __restrict__ idx,
      const float* __restrict__ xg,
      const short* __restrict__ WbIH,
      const short* __restrict__ WbHH,
      const float* __restrict__ b_ih,
      const float* __restrict__ b_hh,
      float* __restrict__ out0,
      float* __restrict__ out1) {
    __shared__ __align__(16) char smem[26112];
    short (*Xb)[136] = (short(*)[136])smem;
    short (*Hb)[136] = (short(*)[136])(smem + 8704);
    short (*Vb)[136] = (short(*)[136])(smem + 17408);
    short (*Hn)[136] = (short(*)[136])smem;

    const int t  = threadIdx.x;
    const int rb = blockIdx.x * 32;

    #pragma unroll
    for (int jj = 0; jj < 2; ++jj) {
        int j = t + jj * 512;
        int row = j >> 5, c4 = j & 31;
        int node = idx[rb + row];
        f32x4 xv = *(const f32x4*)(xg + (size_t)(rb + row) * DIM + c4 * 4);
        f32x4 hv = *(const f32x4*)(hidden + (size_t)node * DIM + c4 * 4);
        f32x4 vv = *(const f32x4*)(variance + (size_t)node * DIM + c4 * 4);
        short4_t xs, hs, vs;
        xs.x = f2bf(xv.x); xs.y = f2bf(xv.y); xs.z = f2bf(xv.z); xs.w = f2bf(xv.w);
        hs.x = f2bf(hv.x); hs.y = f2bf(hv.y); hs.z = f2bf(hv.z); hs.w = f2bf(hv.w);
        vs.x = f2bf(vv.x); vs.y = f2bf(vv.y); vs.z = f2bf(vv.z); vs.w = f2bf(vv.w);
        *(short4_t*)&Xb[row][c4 * 4] = xs;
        *(short4_t*)&Hb[row][c4 * 4] = hs;
        *(short4_t*)&Vb[row][c4 * 4] = vs;
    }
    __syncthreads();

    const int w  = t >> 6;
    const int l  = t & 63;
    const int c  = l & 15;
    const int gq = l >> 4;

    f32x4 acc[2][3][2] = {};
    #pragma unroll
    for (int ks = 0; ks < 4; ++ks) {
        const int k0 = ks * 32 + gq * 8;
        short8 a[2][2];
        a[0][0] = *(const short8*)&Xb[c][k0];
        a[1][0] = *(const short8*)&Xb[16 + c][k0];
        a[0][1] = *(const short8*)&Hb[c][k0];
        a[1][1] = *(const short8*)&Hb[16 + c][k0];
        #pragma unroll
        for (int th = 0; th < 3; ++th) {
            const int o = w * 16 + th * 128 + c;
            const short8 bi = *(const short8*)(WbIH + (size_t)o * DIM + k0);
            const short8 bh = *(const short8*)(WbHH + (size_t)o * DIM + k0);
            #pragma unroll
            for (int mt = 0; mt < 2; ++mt) {
                acc[mt][th][0] = __builtin_amdgcn_mfma_f32_16x16x32_bf16(a[mt][0], bi, acc[mt][th][0], 0, 0, 0);
                acc[mt][th][1] = __builtin_amdgcn_mfma_f32_16x16x32_bf16(a[mt][1], bh, acc[mt][th][1], 0, 0, 0);
            }
        }
    }
    __syncthreads();

    const int d = w * 16 + c;
    const float bs_r = b_ih[d]       + b_hh[d];
    const float bs_z = b_ih[d + 128] + b_hh[d + 128];
    const float bi_n = b_ih[d + 256];
    const float bh_n = b_hh[d + 256];
    #pragma unroll
    for (int mt = 0; mt < 2; ++mt) {
        #pragma unroll
        for (int r = 0; r < 4; ++r) {
            const int m = mt * 16 + gq * 4 + r;
            float s_r  = acc[mt][0][0][r] + acc[mt][0][1][r] + bs_r;
            float s_z  = acc[mt][1][0][r] + acc[mt][1][1][r] + bs_z;
            float gi_n = acc[mt][2][0][r] + bi_n;
            float gh_n = acc[mt][2][1][r] + bh_n;
            float rg = 1.f / (1.f + __expf(-s_r));
            float zg = 1.f / (1.f + __expf(-s_z));
            float aa = gi_n + rg * gh_n;
            float n  = 1.f - 2.f / (__expf(2.f * aa) + 1.f);
            float h  = bf2f(Hb[m][d]);
            Hn[m][d] = f2bf((1.f - zg) * n + zg * h);
        }
    }
    __syncthreads();

    #pragma unroll
    for (int jj = 0; jj < 2; ++jj) {
        int j = t + jj * 512;
        int row = j >> 5, c4 = j & 31;
        int node = idx[rb + row];
        size_t off = (size_t)node * DIM + c4 * 4;
        short4_t hns = *(short4_t*)&Hn[row][c4 * 4];
        short4_t hs  = *(short4_t*)&Hb[row][c4 * 4];
        short4_t vs  = *(short4_t*)&Vb[row][c4 * 4];
        f32x4 hn, var;
        hn.x = bf2f(hns.x); hn.y = bf2f(hns.y); hn.z = bf2f(hns.z); hn.w = bf2f(hns.w);
        float dx = hn.x - bf2f(hs.x), dy = hn.y - bf2f(hs.y);
        float dz = hn.z - bf2f(hs.z), dw = hn.w - bf2f(hs.w);
        var.x = 0.9f * bf2f(vs.x) + 0.1f * dx * dx;
        var.y = 0.9f * bf2f(vs.y) + 0.1f * dy * dy;
        var.z = 0.9f * bf2f(vs.z) + 0.1f * dz * dz;
        var.w = 0.9f * bf2f(vs.w) + 0.1f * dw * dw;
        *(f32x4*)(out0 + off) = hn;
        *(f32x4*)(out1 + off) = var;
    }
}

// -------------------------------------------------------------- launch ----
extern "C" void kernel_launch(void* const* d_in, const int* in_sizes, int n_in,
                              void* d_out, int out_size, void* d_ws, size_t ws_size,
                              hipStream_t stream) {
    const float* hidden   = (const float*)d_in[0];
    const float* variance = (const float*)d_in[1];
    const int*   idx      = (const int*)d_in[2];
    const float* x        = (const float*)d_in[3];
    const float* Wih      = (const float*)d_in[4];
    const float* Whh      = (const float*)d_in[5];
    const float* bih      = (const float*)d_in[6];
    const float* bhh      = (const float*)d_in[7];
    float* out0 = (float*)d_out;
    float* out1 = out0 + (size_t)NUM_NODES * DIM;

    const size_t invB  = (size_t)NUM_NODES * 4;          // 2,000,000
    const size_t maskB = (size_t)NUM_NODES;              // 500,000
    const size_t wB    = (size_t)3 * DIM * DIM * 2;      // 196,608 per matrix

    const bool full = ws_size >= invB + 2 * wB;          // streaming path
    const bool mid  = !full && ws_size >= maskB + 16 + 2 * wB;

    if (full) {
        int*   inv  = (int*)d_ws;
        short* WbIH = (short*)((char*)d_ws + invB);      // invB % 16 == 0
        short* WbHH = WbIH + 3 * DIM * DIM;
        k_init<<<(NUM_NODES + 255) / 256, 256, 0, stream>>>(
            inv, nullptr, Wih, Whh, WbIH, WbHH);
        k_scatter<<<BATCH / 256, 256, 0, stream>>>(inv, nullptr, idx);
        k_stream<<<NBLK, 512, 0, stream>>>(hidden, variance, inv, x,
                                           WbIH, WbHH, bih, bhh, out0, out1);
    } else if (mid) {
        unsigned char* mask = (unsigned char*)d_ws;
        short* WbIH = (short*)((char*)d_ws + ((maskB + 15) & ~size_t(15)));
        short* WbHH = WbIH + 3 * DIM * DIM;
        k_init<<<(NUM_NODES + 255) / 256, 256, 0, stream>>>(
            nullptr, mask, Wih, Whh, WbIH, WbHH);
        k_scatter<<<BATCH / 256, 256, 0, stream>>>(nullptr, mask, idx);
        k_copy<<<(NUM_NODES * 16) / 256, 256, 0, stream>>>(
            hidden, variance, mask, out0, out1);
        k_gru<<<BATCH / 32, 512, 0, stream>>>(hidden, variance, idx, x,
                                              WbIH, WbHH, bih, bhh, out0, out1);
    } else {
        short* WbIH = (short*)d_ws;
        short* WbHH = WbIH + 3 * DIM * DIM;
        k_init<<<(NUM_NODES + 255) / 256, 256, 0, stream>>>(
            nullptr, nullptr, Wih, Whh, WbIH, WbHH);
        k_copy<<<(NUM_NODES * 16) / 256, 256, 0, stream>>>(
            hidden, variance, nullptr, out0, out1);
        k_gru<<<BATCH / 32, 512, 0, stream>>>(hidden, variance, idx, x,
                                              WbIH, WbHH, bih, bhh, out0, out1);
    }
}